// Round 7
// baseline (136.438 us; speedup 1.0000x reference)
//
#include <hip/hip_runtime.h>
#include <hip/hip_fp16.h>
#include <math.h>

// Round 7: ABLATION PROBE round. Rounds 2/4/5/6 all plateau at ~18 us kernel
// time regardless of inner-loop cost or occupancy -> the time is somewhere my
// model doesn't see. Three dispatches:
//   A: staging phase only, x10 reps, sink to d_ws   (counters visible >40us)
//   B: main loop only,     x6 reps,  stores to d_ws (counters visible >40us)
//   C: the real round-6 kernel, writes d_out (validated output)
// A/B write only scratch; C fully overwrites d_out; all deterministic.

constexpr int D = 64;
constexpr int BCHUNK = 8;
constexpr int NT = 256;
constexpr int ROWS = 512;
constexpr int PADH = 72;
constexpr int R_A = 10;
constexpr int R_B = 6;

union H4 { float4 f; __half2 h[4]; };
union H2 { float2 f; __half2 h[2]; };

// ---------------- Probe A: staging only ----------------
__global__ __launch_bounds__(NT, 4)
void probeA(const float* __restrict__ q, const float* __restrict__ X,
            const float* __restrict__ fw, float* __restrict__ sink, int N) {
    __shared__ float ws[D];
    __shared__ __align__(16) __half qs[BCHUNK][D];
    __shared__ __align__(16) __half xbuf[4][64 * PADH];
    const int t = threadIdx.x, w = t >> 6, l = t & 63;
    const int nwg = gridDim.x, cpx = nwg >> 3;
    const int wg = (blockIdx.x & 7) * cpx + (blockIdx.x >> 3);
    const int nbase = (wg >> 3) * ROWS;
    const int bbase = (wg & 7) * BCHUNK;

    if (t < D) { float x = fw[t]; ws[t] = fmaxf(x, 0.f) + log1pf(expf(-fabsf(x))); }
    __syncthreads();
    const float2* q2 = reinterpret_cast<const float2*>(q);
    if (t < BCHUNK * 32) {
        const float2 v = q2[(size_t)bbase * 32 + t];
        const int d = (t & 31) * 2;
        *reinterpret_cast<__half2*>(&qs[t >> 5][d]) =
            __floats2half2_rn(v.x * ws[d], v.y * ws[d + 1]);
    }
    const int col = l & 15, rsub = l >> 4;
    const float4 wv = {ws[col*4], ws[col*4+1], ws[col*4+2], ws[col*4+3]};
    __half* wb = xbuf[w];
    const float4* Xv = reinterpret_cast<const float4*>(X);

    __half2 acc = __float2half2_rn(0.f);
    for (int rep = 0; rep < R_A; ++rep) {
        __half2 xr[2][32];
#pragma unroll
        for (int p = 0; p < 2; ++p) {
#pragma unroll
            for (int j = 0; j < 16; ++j) {
                const int r = j * 4 + rsub;
                int grow = nbase + w * 128 + p * 64 + r;
                grow = grow < N ? grow : N - 1;
                const float4 v = Xv[(size_t)grow * 16 + col];
                H2 u;
                u.h[0] = __floats2half2_rn(v.x * wv.x, v.y * wv.y);
                u.h[1] = __floats2half2_rn(v.z * wv.z, v.w * wv.w);
                *reinterpret_cast<float2*>(&wb[r * PADH + col * 4]) = u.f;
            }
            asm volatile("s_waitcnt lgkmcnt(0)" ::: "memory");
#pragma unroll
            for (int i = 0; i < 8; ++i) {
                H4 u;
                u.f = *reinterpret_cast<const float4*>(&wb[l * PADH + i * 8]);
#pragma unroll
                for (int k = 0; k < 4; ++k) xr[p][i*4+k] = u.h[k];
            }
            asm volatile("s_waitcnt lgkmcnt(0)" ::: "memory");
        }
#pragma unroll
        for (int p = 0; p < 2; ++p)
#pragma unroll
            for (int j = 0; j < 32; ++j) acc = __hadd2(acc, xr[p][j]);
    }
    sink[(size_t)blockIdx.x * NT + t] =
        __low2float(acc) + __high2float(acc) + (float)qs[0][t & 63];
}

// ---------------- Probe B: main loop only ----------------
__global__ __launch_bounds__(NT, 4)
void probeB(const float* __restrict__ q, const float* __restrict__ fw,
            float* __restrict__ outws, int N) {
    __shared__ float ws[D];
    __shared__ __align__(16) __half qs[BCHUNK][D];
    const int t = threadIdx.x, w = t >> 6, l = t & 63;
    const int nwg = gridDim.x, cpx = nwg >> 3;
    const int wg = (blockIdx.x & 7) * cpx + (blockIdx.x >> 3);
    const int nbase = (wg >> 3) * ROWS;
    const int bbase = (wg & 7) * BCHUNK;

    if (t < D) { float x = fw[t]; ws[t] = fmaxf(x, 0.f) + log1pf(expf(-fabsf(x))); }
    __syncthreads();
    const float2* q2 = reinterpret_cast<const float2*>(q);
    if (t < BCHUNK * 32) {
        const float2 v = q2[(size_t)bbase * 32 + t];
        const int d = (t & 31) * 2;
        *reinterpret_cast<__half2*>(&qs[t >> 5][d]) =
            __floats2half2_rn(v.x * ws[d], v.y * ws[d + 1]);
    }
    __syncthreads();

    // cheap deterministic xr stand-in (real kernel has these in VGPRs too)
    __half2 xr[2][32];
#pragma unroll
    for (int j = 0; j < 32; ++j) {
        xr[0][j] = __floats2half2_rn(ws[2*j] + (float)l, ws[2*j+1] - (float)l);
        xr[1][j] = __floats2half2_rn(ws[2*j] - (float)l, ws[2*j+1] + (float)l);
    }
    const int nA = nbase + w * 128 + l;
    const int nB = nA + 64;
    const float4* qs4 = reinterpret_cast<const float4*>(qs);

    for (int rep = 0; rep < R_B; ++rep) {
        asm volatile("" ::: "memory");
#pragma unroll 2
        for (int bi = 0; bi < BCHUNK; ++bi) {
            const __half2 z = __float2half2_rn(0.f);
            __half2 a0 = z, a1 = z, b0 = z, b1 = z;
#pragma unroll
            for (int i = 0; i < 8; ++i) {
                H4 qv; qv.f = qs4[bi * 8 + i];
#pragma unroll
                for (int k = 0; k < 4; ++k) {
                    const __half2 dA = __habs2(__hsub2(qv.h[k], xr[0][i*4+k]));
                    const __half2 dB = __habs2(__hsub2(qv.h[k], xr[1][i*4+k]));
                    if (k & 1) { a1 = __hadd2(a1, dA); b1 = __hadd2(b1, dB); }
                    else       { a0 = __hadd2(a0, dA); b0 = __hadd2(b0, dB); }
                }
            }
            const __half2 sa = __hadd2(a0, a1), sb = __hadd2(b0, b1);
            float* orow = outws + (size_t)(bbase + bi) * N;
            if (nA < N) orow[nA] = __low2float(sa) + __high2float(sa);
            if (nB < N) orow[nB] = __low2float(sb) + __high2float(sb);
        }
    }
}

// ---------------- C: real kernel (round 6, unchanged) ----------------
__global__ __launch_bounds__(NT, 4)
void fdist_kernel(const float* __restrict__ q,
                  const float* __restrict__ X,
                  const float* __restrict__ fw,
                  float* __restrict__ out, int N) {
    __shared__ float ws[D];
    __shared__ __align__(16) __half qs[BCHUNK][D];
    __shared__ __align__(16) __half xbuf[4][64 * PADH];

    const int t = threadIdx.x;
    const int w = t >> 6, l = t & 63;
    const int nwg = gridDim.x, cpx = nwg >> 3;
    const int wg = (blockIdx.x & 7) * cpx + (blockIdx.x >> 3);
    const int nbase = (wg >> 3) * ROWS;
    const int bbase = (wg & 7) * BCHUNK;

    if (t < D) { float x = fw[t]; ws[t] = fmaxf(x, 0.f) + log1pf(expf(-fabsf(x))); }
    __syncthreads();

    const float2* q2 = reinterpret_cast<const float2*>(q);
    if (t < BCHUNK * 32) {
        const float2 v = q2[(size_t)bbase * 32 + t];
        const int d = (t & 31) * 2;
        *reinterpret_cast<__half2*>(&qs[t >> 5][d]) =
            __floats2half2_rn(v.x * ws[d], v.y * ws[d + 1]);
    }

    const int col = l & 15, rsub = l >> 4;
    const float4 wv = {ws[col*4], ws[col*4+1], ws[col*4+2], ws[col*4+3]};

    __half* wb = xbuf[w];
    const float4* Xv = reinterpret_cast<const float4*>(X);
    __half2 xr[2][32];

#pragma unroll
    for (int p = 0; p < 2; ++p) {
#pragma unroll
        for (int j = 0; j < 16; ++j) {
            const int r = j * 4 + rsub;
            int grow = nbase + w * 128 + p * 64 + r;
            grow = grow < N ? grow : N - 1;
            const float4 v = Xv[(size_t)grow * 16 + col];
            H2 u;
            u.h[0] = __floats2half2_rn(v.x * wv.x, v.y * wv.y);
            u.h[1] = __floats2half2_rn(v.z * wv.z, v.w * wv.w);
            *reinterpret_cast<float2*>(&wb[r * PADH + col * 4]) = u.f;
        }
        asm volatile("s_waitcnt lgkmcnt(0)" ::: "memory");
#pragma unroll
        for (int i = 0; i < 8; ++i) {
            H4 u;
            u.f = *reinterpret_cast<const float4*>(&wb[l * PADH + i * 8]);
#pragma unroll
            for (int k = 0; k < 4; ++k) xr[p][i * 4 + k] = u.h[k];
        }
        asm volatile("s_waitcnt lgkmcnt(0)" ::: "memory");
    }
    __syncthreads();

    const int nA = nbase + w * 128 + l;
    const int nB = nA + 64;
    const float4* qs4 = reinterpret_cast<const float4*>(qs);

#pragma unroll 2
    for (int bi = 0; bi < BCHUNK; ++bi) {
        const __half2 z = __float2half2_rn(0.f);
        __half2 a0 = z, a1 = z, b0 = z, b1 = z;
#pragma unroll
        for (int i = 0; i < 8; ++i) {
            H4 qv; qv.f = qs4[bi * 8 + i];
#pragma unroll
            for (int k = 0; k < 4; ++k) {
                const __half2 dA = __habs2(__hsub2(qv.h[k], xr[0][i * 4 + k]));
                const __half2 dB = __habs2(__hsub2(qv.h[k], xr[1][i * 4 + k]));
                if (k & 1) { a1 = __hadd2(a1, dA); b1 = __hadd2(b1, dB); }
                else       { a0 = __hadd2(a0, dA); b0 = __hadd2(b0, dB); }
            }
        }
        const __half2 sa = __hadd2(a0, a1), sb = __hadd2(b0, b1);
        float* orow = out + (size_t)(bbase + bi) * N;
        if (nA < N) orow[nA] = __low2float(sa) + __high2float(sa);
        if (nB < N) orow[nB] = __low2float(sb) + __high2float(sb);
    }
}

extern "C" void kernel_launch(void* const* d_in, const int* in_sizes, int n_in,
                              void* d_out, int out_size, void* d_ws, size_t ws_size,
                              hipStream_t stream) {
    const float* q  = (const float*)d_in[0];
    const float* X  = (const float*)d_in[1];
    const float* fw = (const float*)d_in[2];
    float* out = (float*)d_out;
    float* wsf = (float*)d_ws;

    const int B = in_sizes[0] / D;  // 64
    const int N = in_sizes[1] / D;  // 50000

    const int nxblk = (N + ROWS - 1) / ROWS;      // 98
    const int nwg = nxblk * (B / BCHUNK);         // 784

    probeA<<<dim3(nwg), dim3(NT), 0, stream>>>(q, X, fw, wsf, N);
    probeB<<<dim3(nwg), dim3(NT), 0, stream>>>(q, fw, wsf, N);
    fdist_kernel<<<dim3(nwg), dim3(NT), 0, stream>>>(q, X, fw, out, N);
}

// Round 9
// 68.189 us; speedup vs baseline: 2.0009x; 2.0009x over previous
//
#include <hip/hip_runtime.h>
#include <math.h>

// dist[b,n] = sum_d softplus(fw[d]) * |q[b,d] - X[n,d]|
//
// Round 9: LANE = BATCH, corrected. Lane l owns batch row l (B=64==wave).
// q row AND softplus weights both live in VGPRs (64+64); X[n][*] is wave-
// uniform -> scalar pipe (s_load dwordx16). Inner op pair per element:
//   tmp = q - x        v_sub_f32 (x = SGPR operand, legal 1-SGPR)
//   a   = fma(w,|tmp|) v_fma_f32 with abs modifier
// = 2 VALU/elem, numerically IDENTICAL to reference (round-8's bug was
// scaling q but not X; this form needs no operand folding at all).
// No LDS, no barriers, no b-tiling: each X row read once chip-wide.
// m204 bijective XCD swizzle so n-adjacent blocks share an XCD and the
// per-lane 64B half-line writes combine into full 128B lines in one L2.

constexpr int D = 64;
constexpr int RPW = 16;   // X rows per wave; 50000/16 = 3125 blocks exactly

__global__ __launch_bounds__(64, 3)
void fdist_kernel(const float* __restrict__ q,
                  const float* __restrict__ X,
                  const float* __restrict__ fw,
                  float* __restrict__ out, int N, int B) {
    const int l = threadIdx.x;              // lane == batch index b

    // m204 bijective XCD-chunked swizzle (works for nwg % 8 != 0)
    const int nwg = gridDim.x;
    const int q8 = nwg >> 3, r8 = nwg & 7;
    const int xcd = blockIdx.x & 7, pos = blockIdx.x >> 3;
    const int wg = (xcd < r8 ? xcd * (q8 + 1) : r8 * (q8 + 1) + (xcd - r8) * q8) + pos;
    const int nbase = wg * RPW;

    // ---- init: lane l holds q row l and softplus(fw), both in VGPRs ----
    const float4* q4 = reinterpret_cast<const float4*>(q);
    const float4* fw4 = reinterpret_cast<const float4*>(fw);
    const int ql = (l < B ? l : B - 1);
    float4 qr[16], wv[16];
#pragma unroll
    for (int c = 0; c < 16; ++c) {
        const float4 f = fw4[c];            // uniform
        wv[c].x = fmaxf(f.x, 0.f) + log1pf(expf(-fabsf(f.x)));
        wv[c].y = fmaxf(f.y, 0.f) + log1pf(expf(-fabsf(f.y)));
        wv[c].z = fmaxf(f.z, 0.f) + log1pf(expf(-fabsf(f.z)));
        wv[c].w = fmaxf(f.w, 0.f) + log1pf(expf(-fabsf(f.w)));
        qr[c] = q4[(size_t)ql * 16 + c];    // per-lane, 16 KB total, L2-hot
    }

    const float4* X4 = reinterpret_cast<const float4*>(X);
    float* orow = out + (size_t)l * N;      // this lane's output row (b = l)
    const bool bvalid = (l < B);

    // ---- main loop: X row via wave-uniform scalar loads (64 SGPRs/row) ----
#pragma unroll 1
    for (int r = 0; r < RPW; ++r) {
        const int n = nbase + r;
        const int rn = (n < N) ? n : N - 1;
        float a0 = 0.f, a1 = 0.f, a2 = 0.f, a3 = 0.f;
#pragma unroll
        for (int c = 0; c < 16; ++c) {
            const float4 xc = X4[(size_t)rn * 16 + c];   // uniform -> s_load
            a0 = fmaf(wv[c].x, fabsf(qr[c].x - xc.x), a0);
            a1 = fmaf(wv[c].y, fabsf(qr[c].y - xc.y), a1);
            a2 = fmaf(wv[c].z, fabsf(qr[c].z - xc.z), a2);
            a3 = fmaf(wv[c].w, fabsf(qr[c].w - xc.w), a3);
        }
        if (bvalid && n < N) orow[n] = (a0 + a1) + (a2 + a3);
    }
}

extern "C" void kernel_launch(void* const* d_in, const int* in_sizes, int n_in,
                              void* d_out, int out_size, void* d_ws, size_t ws_size,
                              hipStream_t stream) {
    const float* q  = (const float*)d_in[0];
    const float* X  = (const float*)d_in[1];
    const float* fw = (const float*)d_in[2];
    float* out = (float*)d_out;

    const int B = in_sizes[0] / D;  // 64
    const int N = in_sizes[1] / D;  // 50000

    const int nblk = (N + RPW - 1) / RPW;   // 3125 one-wave blocks
    fdist_kernel<<<dim3(nblk), dim3(64), 0, stream>>>(q, X, fw, out, N, B);
}